// Round 14
// baseline (266.151 us; speedup 1.0000x reference)
//
#include <hip/hip_runtime.h>
#include <cstdint>
#include <cstddef>

#define DF 128
#define PB 512        // partition blocks
#define RSH 8         // bucket = node >> RSH
#define RNG 256       // nodes per bucket
#define CAP 6144      // LDS staging capacity (edges) per bucket
#define SCH 4096      // scan elements per block

typedef short bf16x8 __attribute__((ext_vector_type(8)));
typedef float f32x4 __attribute__((ext_vector_type(4)));

// ---------------- bf16 helpers (RNE) ----------------
__device__ __forceinline__ unsigned short f2b(float f) {
  unsigned u = __builtin_bit_cast(unsigned, f);
  u = (u + 0x7FFFu + ((u >> 16) & 1u)) >> 16;
  return (unsigned short)u;
}
__device__ __forceinline__ float b2f(unsigned short h) {
  return __builtin_bit_cast(float, (unsigned)h << 16);
}
__device__ __forceinline__ unsigned pack2(float lo, float hi) {
  return (unsigned)f2b(lo) | ((unsigned)f2b(hi) << 16);
}

// ---------------- edge dtype handling (int32 vs int64 storage) ----------------
__device__ __forceinline__ int edge_at(const void* ei, long long idx, int is32) {
  return is32 ? ((const int*)ei)[idx] : (int)((const long long*)ei)[idx];
}

// Per-block self-detection: sample odd u32 words of this block's chunk under the
// int64 hypothesis (values < 2^31 -> hi word 0). Indices stay < 2E so no OOB
// under the int32 hypothesis. Deterministic per replay.
__device__ __forceinline__ int detect_is32(const void* ei, long long lo, long long hi,
                                           int* s_flag) {
  int t = threadIdx.x;
  if (t == 0) *s_flag = 0;
  __syncthreads();
  int bad = 0;
  long long cap = lo + 2048; if (cap > hi) cap = hi;
  for (long long e = lo + t; e < cap; e += blockDim.x)
    bad |= (((const unsigned*)ei)[2 * e + 1] != 0);
  if (bad) atomicOr(s_flag, 1);
  __syncthreads();
  return *s_flag;
}

// ---------------- L1: per-block bucket histograms (LDS atomics only) ----------
__global__ __launch_bounds__(256) void part_count_kernel(
    const void* __restrict__ ei, long long E, int nbuck, int chunk,
    int* __restrict__ H) {
  __shared__ int hd[512], hs[512], s_flag;
  int blk = blockIdx.x, t = threadIdx.x;
  for (int i = t; i < 512; i += 256) { hd[i] = 0; hs[i] = 0; }
  long long lo = (long long)blk * chunk;
  long long hi = lo + chunk; if (hi > E) hi = E;
  int is32 = detect_is32(ei, lo, hi, &s_flag);   // includes syncthreads
  for (long long e = lo + t; e < hi; e += 256) {
    int s = edge_at(ei, e, is32);
    int d = edge_at(ei, E + e, is32);
    atomicAdd(&hs[s >> RSH], 1);
    atomicAdd(&hd[d >> RSH], 1);
  }
  __syncthreads();
  for (int b = t; b < nbuck; b += 256) {
    H[(size_t)b * PB + blk] = hd[b];
    H[((size_t)nbuck + b) * PB + blk] = hs[b];
  }
}

// ---------------- wave scan helper ----------------
__device__ __forceinline__ int wave_incl_scan(int v, int lane) {
#pragma unroll
  for (int off = 1; off < 64; off <<= 1) {
    int t = __shfl_up(v, off, 64);
    if (lane >= off) v += t;
  }
  return v;
}

// ---- single-kernel decoupled-lookback exclusive scan (+ W-prep side blocks) ---
// blocks [0,nblk): scan 4096 elems each, publish (sum<<2|state) in desc,
// state 1=aggregate 2=inclusive; lookback walks lower ids (dispatch-ordered ->
// forward progress). blocks [nblk, nblk+8): W swizzle prep (1024 items each).
// W layout: [w(2)][part(2)][tile(32)=jb*4+ks][lane(64)] x 16B (8 bf16, contig k)
__global__ __launch_bounds__(1024) void scan_lookback_kernel(
    const int* __restrict__ H, int* __restrict__ Hs, unsigned* __restrict__ desc,
    int m, int nblk,
    const float* __restrict__ W1, const float* __restrict__ W2,
    unsigned short* __restrict__ Wswz) {
  if ((int)blockIdx.x >= nblk) {
    int chunk = ((int)blockIdx.x - nblk) * 1024 + threadIdx.x;   // 0..8191
    if (chunk < 8192) {
      int w = chunk >> 12;
      int rem = chunk & 4095;
      int part = rem >> 11;
      int tt = (rem >> 6) & 31;
      int l = rem & 63;
      int jb = tt >> 2, ks = tt & 3;
      const float* W = w ? W2 : W1;
      int c = jb * 16 + (l & 15);
      int k0 = ks * 32 + ((l >> 4) << 3);
      unsigned v[4];
#pragma unroll
      for (int p = 0; p < 4; ++p) {
        float f0 = W[(size_t)(k0 + 2 * p) * DF + c];
        float f1 = W[(size_t)(k0 + 2 * p + 1) * DF + c];
        unsigned short h0 = f2b(f0), h1 = f2b(f1);
        unsigned short o0 = part ? f2b(f0 - b2f(h0)) : h0;
        unsigned short o1 = part ? f2b(f1 - b2f(h1)) : h1;
        v[p] = (unsigned)o0 | ((unsigned)o1 << 16);
      }
      uint4 o; o.x = v[0]; o.y = v[1]; o.z = v[2]; o.w = v[3];
      ((uint4*)Wswz)[chunk] = o;
    }
    return;
  }
  __shared__ int wsum[16];
  __shared__ int s_excl;
  int tid = threadIdx.x, lane = tid & 63, wid = tid >> 6;
  int base = blockIdx.x * SCH + tid * 4;
  int v0 = (base + 0 < m) ? H[base + 0] : 0;
  int v1 = (base + 1 < m) ? H[base + 1] : 0;
  int v2 = (base + 2 < m) ? H[base + 2] : 0;
  int v3 = (base + 3 < m) ? H[base + 3] : 0;
  int p0 = v0, p1 = p0 + v1, p2 = p1 + v2, p3 = p2 + v3;
  int ws = wave_incl_scan(p3, lane);
  if (lane == 63) wsum[wid] = ws;
  __syncthreads();
  if (wid == 0) {
    int x = (lane < 16) ? wsum[lane] : 0;
    x = wave_incl_scan(x, lane);
    if (lane < 16) wsum[lane] = x;
  }
  __syncthreads();
  if (tid == 0) {
    int S = wsum[15];
    if (blockIdx.x == 0) {
      __hip_atomic_store(&desc[0], ((unsigned)S << 2) | 2u,
                         __ATOMIC_RELEASE, __HIP_MEMORY_SCOPE_AGENT);
      s_excl = 0;
    } else {
      __hip_atomic_store(&desc[blockIdx.x], ((unsigned)S << 2) | 1u,
                         __ATOMIC_RELEASE, __HIP_MEMORY_SCOPE_AGENT);
      unsigned ex = 0;
      int j = (int)blockIdx.x - 1;
      for (;;) {
        unsigned d = __hip_atomic_load(&desc[j], __ATOMIC_ACQUIRE, __HIP_MEMORY_SCOPE_AGENT);
        unsigned stt = d & 3u;
        if (stt == 2u) { ex += (d >> 2); break; }
        if (stt == 1u) { ex += (d >> 2); --j; }
      }
      __hip_atomic_store(&desc[blockIdx.x], (((unsigned)S + ex) << 2) | 2u,
                         __ATOMIC_RELEASE, __HIP_MEMORY_SCOPE_AGENT);
      s_excl = (int)ex;
    }
  }
  __syncthreads();
  int off = (wid > 0 ? wsum[wid - 1] : 0) + (ws - p3) + s_excl;
  if (base + 0 < m) Hs[base + 1] = off + p0;
  if (base + 1 < m) Hs[base + 2] = off + p1;
  if (base + 2 < m) Hs[base + 3] = off + p2;
  if (base + 3 < m) Hs[base + 4] = off + p3;
  if (blockIdx.x == 0 && tid == 0) Hs[0] = 0;
}

// ---------------- L1b: scatter into bucket segments (LDS ranks, plain stores) --
__global__ __launch_bounds__(256) void part_scatter_kernel(
    const void* __restrict__ ei, long long E, int nbuck, int chunk,
    const int* __restrict__ Hs, unsigned* __restrict__ pack_d,
    unsigned char* __restrict__ src_loc) {
  __shared__ int hd[512], hs[512], bd[512], bs[512];
  __shared__ int s_flag;
  int blk = blockIdx.x, t = threadIdx.x;
  for (int i = t; i < 512; i += 256) { hd[i] = 0; hs[i] = 0; }
  for (int b = t; b < nbuck; b += 256) {
    bd[b] = Hs[(size_t)b * PB + blk];
    bs[b] = Hs[((size_t)nbuck + b) * PB + blk] - (int)E;
  }
  long long lo = (long long)blk * chunk;
  long long hi = lo + chunk; if (hi > E) hi = E;
  int is32 = detect_is32(ei, lo, hi, &s_flag);   // includes syncthreads
  for (long long e = lo + t; e < hi; e += 256) {
    int s = edge_at(ei, e, is32);
    int d = edge_at(ei, E + e, is32);
    int kb = d >> RSH;
    int rd = atomicAdd(&hd[kb], 1);
    pack_d[bd[kb] + rd] = ((unsigned)(d & (RNG - 1)) << 24) | (unsigned)s;
    int ks = s >> RSH;
    int rs = atomicAdd(&hs[ks], 1);
    src_loc[bs[ks] + rs] = (unsigned char)(s & (RNG - 1));
  }
}

// --- L2: per-bucket CSR build (row_ptr, nin, csr_src) + src-deg (nout) ---------
// --- + fused prescale: x1h[node,:] = bf16(in_feat[node,:] * nout[node]) --------
__global__ __launch_bounds__(256) void bucket_build_kernel(
    const unsigned* __restrict__ pack_d, const unsigned char* __restrict__ src_loc,
    const int* __restrict__ Hs, int nbuck, long long E, int n,
    int* __restrict__ row_ptr, float* __restrict__ nin, float* __restrict__ nout,
    int* __restrict__ csr_src,
    const float* __restrict__ in_feat, unsigned short* __restrict__ x1h) {
  __shared__ unsigned stage[CAP];
  __shared__ int cnt[RNG], cur[RNG], woff[4];
  __shared__ float fn[RNG];
  int b = blockIdx.x, t = threadIdx.x;
  int lane = t & 63, wv = t >> 6;
  int start = Hs[(size_t)b * PB];
  int end = Hs[(size_t)(b + 1) * PB];
  int len = end - start;
  cnt[t] = 0;
  __syncthreads();
  bool fits = (len <= CAP);
  for (int i = t; i < len; i += 256) {
    unsigned p = pack_d[start + i];
    if (fits) stage[i] = p;
    atomicAdd(&cnt[p >> 24], 1);
  }
  __syncthreads();
  int dreg = cnt[t];
  int isc = wave_incl_scan(dreg, lane);
  if (lane == 63) woff[wv] = isc;
  __syncthreads();
  int add = 0;
#pragma unroll
  for (int w = 0; w < 4; ++w) if (w < wv) add += woff[w];
  int excl = isc - dreg + add;
  int nd = b * RNG + t;
  if (nd < n) {
    row_ptr[nd] = start + excl;
    nin[nd] = rsqrtf((float)(dreg > 1 ? dreg : 1));
  }
  if (b == (int)gridDim.x - 1 && t == 0) row_ptr[n] = (int)E;
  cur[t] = excl;
  __syncthreads();
  for (int i = t; i < len; i += 256) {
    unsigned p = fits ? stage[i] : pack_d[start + i];
    int dl = (int)(p >> 24);
    int r = atomicAdd(&cur[dl], 1);
    csr_src[start + r] = (int)(p & 0xFFFFFFu);
  }
  // ---- src-degree phase -> nout (reuses cnt after dst phase completes) ----
  __syncthreads();
  cnt[t] = 0;
  __syncthreads();
  int sstart = Hs[(size_t)(nbuck + b) * PB] - (int)E;
  int send = Hs[(size_t)(nbuck + b + 1) * PB] - (int)E;
  for (int i = sstart + t; i < send; i += 256) atomicAdd(&cnt[src_loc[i]], 1);
  __syncthreads();
  float nv = rsqrtf((float)(cnt[t] > 1 ? cnt[t] : 1));
  fn[t] = nv;
  if (nd < n) nout[nd] = nv;
  __syncthreads();
  // ---- fused prescale for this bucket's nodes: 256 nodes x 128 f32 ----
  for (int c = t; c < RNG * DF / 8; c += 256) {
    int jl = c >> 4;                 // local node (chunk covers 8 of 128 cols)
    int node = b * RNG + jl;
    if (node >= n) break;            // trailing nodes only in last bucket
    float s = fn[jl];
    long long base = (long long)node * DF + (c & 15) * 8;
    float4 a = *((const float4*)(in_feat + base));
    float4 bb = *((const float4*)(in_feat + base + 4));
    uint4 o;
    o.x = pack2(a.x * s, a.y * s);
    o.y = pack2(a.z * s, a.w * s);
    o.z = pack2(bb.x * s, bb.y * s);
    o.w = pack2(bb.z * s, bb.w * s);
    *((uint4*)(x1h + base)) = o;
  }
}

// ---------------- aggregation: one wave per dst node, bf16 256B rows -----------
// (R10 half-wave form — proven 60.2us, service-rate floored.)
__global__ __launch_bounds__(256) void aggregate_bf16_kernel(
    const unsigned short* __restrict__ xh, const int* __restrict__ row_ptr,
    const int* __restrict__ csr_src, unsigned short* __restrict__ aggh, int n) {
  int wave = blockIdx.x * (blockDim.x >> 6) + (threadIdx.x >> 6);
  int lane = threadIdx.x & 63;
  if (wave >= n) return;
  int beg = row_ptr[wave], end = row_ptr[wave + 1];
  int deg = end - beg;
  int half = lane >> 5;       // which edge of the pair
  int sub = lane & 31;        // ushort4 slot within the 256B row
  float ax = 0.f, ay = 0.f, az = 0.f, aw = 0.f;
  for (int j0 = 0; j0 < deg; j0 += 64) {
    int li = beg + j0 + lane;
    int idx = csr_src[li < end ? li : (end - 1)];
    int cnt = deg - j0; if (cnt > 64) cnt = 64;
    int tfull = (cnt >> 4) << 3;   // pairs fully valid, in groups of 8
    for (int t0 = 0; t0 < tfull; t0 += 8) {
      ushort4 v[8];
#pragma unroll
      for (int u = 0; u < 8; ++u) {
        int s = __shfl(idx, 2 * (t0 + u) + half, 64);
        v[u] = *((const ushort4*)(xh + (size_t)s * DF) + sub);
      }
#pragma unroll
      for (int u = 0; u < 8; ++u) {
        ax += b2f(v[u].x); ay += b2f(v[u].y);
        az += b2f(v[u].z); aw += b2f(v[u].w);
      }
    }
    int cnt2 = (cnt + 1) >> 1;
    for (int t = tfull; t < cnt2; ++t) {
      int p = 2 * t + half;
      int s = __shfl(idx, p, 64);
      float m = (p < cnt) ? 1.f : 0.f;
      ushort4 v = *((const ushort4*)(xh + (size_t)s * DF) + sub);
      ax += b2f(v.x) * m; ay += b2f(v.y) * m;
      az += b2f(v.z) * m; aw += b2f(v.w) * m;
    }
  }
  ax += __shfl_down(ax, 32, 64);
  ay += __shfl_down(ay, 32, 64);
  az += __shfl_down(az, 32, 64);
  aw += __shfl_down(aw, 32, 64);
  if (half == 0) {
    uint2 pk; pk.x = pack2(ax, ay); pk.y = pack2(az, aw);
    *((uint2*)(aggh + (size_t)wave * DF + sub * 4)) = pk;
  }
}

// ------ MFMA transform: out[r,:] = (nin[r]*(aggh[r,:]@W) + b) * sc_out[r] ------
// Two 16-row stripes per wave per tile (tile = 128 rows): 2x independent MFMA
// chains, B-fragments shared between stripes. W (hi+lo) in 64KiB LDS; epilogue
// stages each 16x64 half through per-wave LDS for 16B-coalesced stores.
template <int BF16OUT>
__global__ __launch_bounds__(256) void transform_mfma_kernel(
    const unsigned short* __restrict__ aggh, const unsigned short* __restrict__ Wswz,
    const float* __restrict__ nin, const float* __restrict__ bias,
    const float* __restrict__ sc_out, void* __restrict__ outp, int n, int ntiles) {
  __shared__ uint4 Wl[4096];          // 64 KiB: [part(2)][tile(32)][lane(64)]
  __shared__ float ost[4][16 * 64];   // 16 KiB: per-wave 16x64 f32 stage
  int tid = threadIdx.x;
  for (int i = tid; i < 4096; i += 256) Wl[i] = ((const uint4*)Wswz)[i];
  __syncthreads();
  int l = tid & 63, wv = tid >> 6;
  int lr = l & 15, lg = l >> 4;
  float* st = ost[wv];
  float bj[8];
#pragma unroll
  for (int jb = 0; jb < 8; ++jb) bj[jb] = bias[jb * 16 + lr];
  for (int tile = blockIdx.x; tile < ntiles; tile += gridDim.x) {
    int rb0 = tile * 128 + wv * 16;
    int rb1 = rb0 + 64;
    bf16x8 a[2][4];
#pragma unroll
    for (int s = 0; s < 2; ++s) {
      int r_eff = (s ? rb1 : rb0) + lr; if (r_eff > n - 1) r_eff = n - 1;
      const unsigned short* arow = aggh + (size_t)r_eff * DF + (lg << 3);
      a[s][0] = *(const bf16x8*)(arow);
      a[s][1] = *(const bf16x8*)(arow + 32);
      a[s][2] = *(const bf16x8*)(arow + 64);
      a[s][3] = *(const bf16x8*)(arow + 96);
    }
    f32x4 acc[2][8];
#pragma unroll
    for (int s = 0; s < 2; ++s)
#pragma unroll
      for (int jb = 0; jb < 8; ++jb) acc[s][jb] = (f32x4){0.f, 0.f, 0.f, 0.f};
#pragma unroll
    for (int ks = 0; ks < 4; ++ks) {
#pragma unroll
      for (int jb = 0; jb < 8; ++jb) {
        bf16x8 bh = *(const bf16x8*)&Wl[(jb * 4 + ks) * 64 + l];
        bf16x8 bl = *(const bf16x8*)&Wl[2048 + (jb * 4 + ks) * 64 + l];
        acc[0][jb] = __builtin_amdgcn_mfma_f32_16x16x32_bf16(a[0][ks], bh, acc[0][jb], 0, 0, 0);
        acc[0][jb] = __builtin_amdgcn_mfma_f32_16x16x32_bf16(a[0][ks], bl, acc[0][jb], 0, 0, 0);
        acc[1][jb] = __builtin_amdgcn_mfma_f32_16x16x32_bf16(a[1][ks], bh, acc[1][jb], 0, 0, 0);
        acc[1][jb] = __builtin_amdgcn_mfma_f32_16x16x32_bf16(a[1][ks], bl, acc[1][jb], 0, 0, 0);
      }
    }
#pragma unroll
    for (int s = 0; s < 2; ++s) {
      int rowbase = s ? rb1 : rb0;
      float ninq[4], soq[4];
#pragma unroll
      for (int q = 0; q < 4; ++q) {
        int r = rowbase + lg * 4 + q;
        ninq[q] = (r < n) ? nin[r] : 0.f;
        soq[q] = (r < n) ? (sc_out ? sc_out[r] : 1.f) : 0.f;
      }
      int rmax = n - rowbase;  // rows valid in this stripe (<=16 at the tail)
#pragma unroll
      for (int h = 0; h < 2; ++h) {
#pragma unroll
        for (int jb4 = 0; jb4 < 4; ++jb4) {
          int jb = h * 4 + jb4;
#pragma unroll
          for (int q = 0; q < 4; ++q) {
            st[(lg * 4 + q) * 64 + jb4 * 16 + lr] =
                (acc[s][jb][q] * ninq[q] + bj[jb]) * soq[q];
          }
        }
        // read back coalesced (same wave; compiler inserts lgkmcnt waits)
        if (BF16OUT) {
#pragma unroll
          for (int it = 0; it < 2; ++it) {
            int id = it * 64 + l;          // 0..127: row(16) x 8-col-group(8)
            int row = id >> 3, c8 = id & 7;
            if (row < rmax) {
              float4 va = *((const float4*)&st[row * 64 + c8 * 8]);
              float4 vb = *((const float4*)&st[row * 64 + c8 * 8 + 4]);
              uint4 o;
              o.x = pack2(va.x, va.y); o.y = pack2(va.z, va.w);
              o.z = pack2(vb.x, vb.y); o.w = pack2(vb.z, vb.w);
              *((uint4*)((unsigned short*)outp + (size_t)(rowbase + row) * DF + h * 64 + c8 * 8)) = o;
            }
          }
        } else {
#pragma unroll
          for (int it = 0; it < 4; ++it) {
            int id = it * 64 + l;          // 0..255: row(16) x float4-group(16)
            int row = id >> 4, c4 = id & 15;
            if (row < rmax) {
              float4 v = *((const float4*)&st[row * 64 + c4 * 4]);
              *((float4*)((float*)outp + (size_t)(rowbase + row) * DF + h * 64 + c4 * 4)) = v;
            }
          }
        }
      }
    }
  }
}

extern "C" void kernel_launch(void* const* d_in, const int* in_sizes, int n_in,
                              void* d_out, int out_size, void* d_ws, size_t ws_size,
                              hipStream_t stream) {
  const float* in_feat = (const float*)d_in[0];
  const void*  ei      = d_in[1];
  const float* W1 = (const float*)d_in[2];
  const float* b1 = (const float*)d_in[3];
  const float* W2 = (const float*)d_in[4];
  const float* b2 = (const float*)d_in[5];
  float* out = (float*)d_out;

  const int N = in_sizes[0] / DF;
  const long long E = in_sizes[1] / 2;
  const int nbuck = (N + RNG - 1) >> RSH;          // 391 for N=100K (must be <=512)
  const int M = 2 * nbuck * PB;                    // histogram array length
  const int NBLK = (M + SCH - 1) / SCH;            // lookback-scan blocks
  const int chunk = (int)((E + PB - 1) / PB);      // edges per partition block
  const int ntiles = (N + 127) / 128;              // 128-row transform tiles

  size_t off = 0;
  auto take = [&](size_t nb) -> char* {
    char* p = (char*)d_ws + off;
    off += (nb + 255) & ~(size_t)255;
    return p;
  };
  int* H          = (int*)take((size_t)M * 4);          // 1.6 MB
  int* Hs         = (int*)take((size_t)(M + 1) * 4);    // 1.6 MB
  unsigned* desc  = (unsigned*)take((size_t)NBLK * 4);
  int* row_ptr    = (int*)take((size_t)(N + 1) * 4);
  float* nout     = (float*)take((size_t)N * 4);
  float* nin      = (float*)take((size_t)N * 4);
  unsigned* pack_d = (unsigned*)take((size_t)E * 4);    // 6.4 MB
  unsigned char* src_loc = (unsigned char*)take((size_t)E); // 1.6 MB
  int* csr_src    = (int*)take((size_t)E * 4);          // 6.4 MB
  unsigned short* x1h = (unsigned short*)take((size_t)N * DF * 2); // 25.6 MB
  unsigned short* h1h = (unsigned short*)take((size_t)N * DF * 2); // 25.6 MB
  unsigned short* aggh = (unsigned short*)take((size_t)N * DF * 2); // 25.6 MB
  unsigned short* Wswz = (unsigned short*)take(2 * 65536);          // 128 KiB
  (void)ws_size; (void)n_in; (void)out_size;

  hipMemsetAsync(desc, 0, (size_t)NBLK * 4, stream);
  part_count_kernel<<<PB, 256, 0, stream>>>(ei, E, nbuck, chunk, H);
  scan_lookback_kernel<<<NBLK + 8, 1024, 0, stream>>>(H, Hs, desc, M, NBLK, W1, W2, Wswz);
  part_scatter_kernel<<<PB, 256, 0, stream>>>(ei, E, nbuck, chunk, Hs, pack_d, src_loc);
  bucket_build_kernel<<<nbuck, 256, 0, stream>>>(pack_d, src_loc, Hs, nbuck, E, N,
                                                 row_ptr, nin, nout, csr_src,
                                                 in_feat, x1h);

  int ab = (N + 3) / 4;  // 4 waves (nodes) per 256-thread block
  // conv1: x1h -> aggh -> h1h = bf16((nin*(aggh@W1)+b1)*dout)
  aggregate_bf16_kernel<<<ab, 256, 0, stream>>>(x1h, row_ptr, csr_src, aggh, N);
  transform_mfma_kernel<1><<<512, 256, 0, stream>>>(aggh, Wswz, nin, b1, nout, h1h, N, ntiles);
  // conv2: h1h -> aggh -> out (f32)
  aggregate_bf16_kernel<<<ab, 256, 0, stream>>>(h1h, row_ptr, csr_src, aggh, N);
  transform_mfma_kernel<0><<<512, 256, 0, stream>>>(aggh, Wswz + 32768, nin, b2, nullptr, out, N, ntiles);
}

// Round 15
// 261.185 us; speedup vs baseline: 1.0190x; 1.0190x over previous
//
#include <hip/hip_runtime.h>
#include <cstdint>
#include <cstddef>

#define DF 128
#define PB 512        // partition blocks
#define RSH 8         // bucket = node >> RSH
#define RNG 256       // nodes per bucket
#define CAP 6144      // LDS staging capacity (edges) per bucket

typedef short bf16x8 __attribute__((ext_vector_type(8)));
typedef float f32x4 __attribute__((ext_vector_type(4)));

// ---------------- bf16 helpers (RNE) ----------------
__device__ __forceinline__ unsigned short f2b(float f) {
  unsigned u = __builtin_bit_cast(unsigned, f);
  u = (u + 0x7FFFu + ((u >> 16) & 1u)) >> 16;
  return (unsigned short)u;
}
__device__ __forceinline__ float b2f(unsigned short h) {
  return __builtin_bit_cast(float, (unsigned)h << 16);
}
__device__ __forceinline__ unsigned pack2(float lo, float hi) {
  return (unsigned)f2b(lo) | ((unsigned)f2b(hi) << 16);
}

// ---------------- edge dtype handling (int32 vs int64 storage) ----------------
__device__ __forceinline__ int edge_at(const void* ei, long long idx, int is32) {
  return is32 ? ((const int*)ei)[idx] : (int)((const long long*)ei)[idx];
}

// Per-block self-detection: sample odd u32 words of this block's chunk under the
// int64 hypothesis (values < 2^31 -> hi word 0). Indices stay < 2E so no OOB
// under the int32 hypothesis. Deterministic per replay.
__device__ __forceinline__ int detect_is32(const void* ei, long long lo, long long hi,
                                           int* s_flag) {
  int t = threadIdx.x;
  if (t == 0) *s_flag = 0;
  __syncthreads();
  int bad = 0;
  long long cap = lo + 2048; if (cap > hi) cap = hi;
  for (long long e = lo + t; e < cap; e += blockDim.x)
    bad |= (((const unsigned*)ei)[2 * e + 1] != 0);
  if (bad) atomicOr(s_flag, 1);
  __syncthreads();
  return *s_flag;
}

// ---------------- L1: per-block bucket histograms (LDS atomics only) ----------
__global__ __launch_bounds__(256) void part_count_kernel(
    const void* __restrict__ ei, long long E, int nbuck, int chunk,
    int* __restrict__ H) {
  __shared__ int hd[512], hs[512], s_flag;
  int blk = blockIdx.x, t = threadIdx.x;
  for (int i = t; i < 512; i += 256) { hd[i] = 0; hs[i] = 0; }
  long long lo = (long long)blk * chunk;
  long long hi = lo + chunk; if (hi > E) hi = E;
  int is32 = detect_is32(ei, lo, hi, &s_flag);   // includes syncthreads
  for (long long e = lo + t; e < hi; e += 256) {
    int s = edge_at(ei, e, is32);
    int d = edge_at(ei, E + e, is32);
    atomicAdd(&hs[s >> RSH], 1);
    atomicAdd(&hd[d >> RSH], 1);
  }
  __syncthreads();
  for (int b = t; b < nbuck; b += 256) {
    H[(size_t)b * PB + blk] = hd[b];
    H[((size_t)nbuck + b) * PB + blk] = hs[b];
  }
}

// ---------------- exclusive scan (3-kernel, shfl-based) ----------------
__device__ __forceinline__ int wave_incl_scan(int v, int lane) {
#pragma unroll
  for (int off = 1; off < 64; off <<= 1) {
    int t = __shfl_up(v, off, 64);
    if (lane >= off) v += t;
  }
  return v;
}

// blocks [0, nb): 1024-thread chunk sums (4096 elems each). blocks [nb, nb+8):
// W swizzle prep (1024 items each, 8192 total).
// W layout: [w(2)][part(2)][tile(32)=jb*4+ks][lane(64)] x 16B (8 bf16, contig k)
__global__ void chunk_sum_kernel(const int* __restrict__ deg, int* __restrict__ partials,
                                 int n, int nb,
                                 const float* __restrict__ W1, const float* __restrict__ W2,
                                 unsigned short* __restrict__ Wswz) {
  if ((int)blockIdx.x >= nb) {
    int chunk = ((int)blockIdx.x - nb) * 1024 + threadIdx.x;   // 0..8191
    if (chunk < 8192) {
      int w = chunk >> 12;
      int rem = chunk & 4095;
      int part = rem >> 11;
      int tt = (rem >> 6) & 31;
      int l = rem & 63;
      int jb = tt >> 2, ks = tt & 3;
      const float* W = w ? W2 : W1;
      int c = jb * 16 + (l & 15);
      int k0 = ks * 32 + ((l >> 4) << 3);
      unsigned v[4];
#pragma unroll
      for (int p = 0; p < 4; ++p) {
        float f0 = W[(size_t)(k0 + 2 * p) * DF + c];
        float f1 = W[(size_t)(k0 + 2 * p + 1) * DF + c];
        unsigned short h0 = f2b(f0), h1 = f2b(f1);
        unsigned short o0 = part ? f2b(f0 - b2f(h0)) : h0;
        unsigned short o1 = part ? f2b(f1 - b2f(h1)) : h1;
        v[p] = (unsigned)o0 | ((unsigned)o1 << 16);
      }
      uint4 o; o.x = v[0]; o.y = v[1]; o.z = v[2]; o.w = v[3];
      ((uint4*)Wswz)[chunk] = o;
    }
    return;
  }
  __shared__ int wsum[16];
  int tid = threadIdx.x, lane = tid & 63, wid = tid >> 6;
  int base = blockIdx.x * 4096 + tid * 4;
  int s = 0;
#pragma unroll
  for (int q = 0; q < 4; ++q) { int i = base + q; if (i < n) s += deg[i]; }
#pragma unroll
  for (int off = 32; off; off >>= 1) s += __shfl_down(s, off, 64);
  if (lane == 0) wsum[wid] = s;
  __syncthreads();
  if (tid == 0) {
    int t = 0;
#pragma unroll
    for (int w = 0; w < 16; ++w) t += wsum[w];
    partials[blockIdx.x] = t;
  }
}

__global__ void scan_partials_kernel(int* __restrict__ partials, int nb) {
  int lane = threadIdx.x;
  int carry = 0;
  for (int base = 0; base < nb; base += 64) {
    int i = base + lane;
    int v = (i < nb) ? partials[i] : 0;
    int s = wave_incl_scan(v, lane);
    if (i < nb) partials[i] = s - v + carry;  // exclusive + carry
    carry += __shfl(s, 63, 64);
  }
}

__global__ void scan_chunk_kernel(const int* __restrict__ deg, const int* __restrict__ chunk_off,
                                  int* __restrict__ row_ptr, int n) {
  __shared__ int wsum[16];
  int tid = threadIdx.x, lane = tid & 63, wid = tid >> 6;
  int base = blockIdx.x * 4096 + tid * 4;
  int v0 = (base + 0 < n) ? deg[base + 0] : 0;
  int v1 = (base + 1 < n) ? deg[base + 1] : 0;
  int v2 = (base + 2 < n) ? deg[base + 2] : 0;
  int v3 = (base + 3 < n) ? deg[base + 3] : 0;
  int p0 = v0, p1 = p0 + v1, p2 = p1 + v2, p3 = p2 + v3;
  int ws = wave_incl_scan(p3, lane);
  if (lane == 63) wsum[wid] = ws;
  __syncthreads();
  if (wid == 0) {
    int x = (lane < 16) ? wsum[lane] : 0;
    x = wave_incl_scan(x, lane);
    if (lane < 16) wsum[lane] = x;
  }
  __syncthreads();
  int off = (wid > 0 ? wsum[wid - 1] : 0) + (ws - p3) + chunk_off[blockIdx.x];
  if (base + 0 < n) row_ptr[base + 1] = off + p0;
  if (base + 1 < n) row_ptr[base + 2] = off + p1;
  if (base + 2 < n) row_ptr[base + 3] = off + p2;
  if (base + 3 < n) row_ptr[base + 4] = off + p3;
  if (blockIdx.x == 0 && tid == 0) row_ptr[0] = 0;
}

// ---------------- L1b: scatter into bucket segments (LDS ranks, plain stores) --
__global__ __launch_bounds__(256) void part_scatter_kernel(
    const void* __restrict__ ei, long long E, int nbuck, int chunk,
    const int* __restrict__ Hs, unsigned* __restrict__ pack_d,
    unsigned char* __restrict__ src_loc) {
  __shared__ int hd[512], hs[512], bd[512], bs[512];
  __shared__ int s_flag;
  int blk = blockIdx.x, t = threadIdx.x;
  for (int i = t; i < 512; i += 256) { hd[i] = 0; hs[i] = 0; }
  for (int b = t; b < nbuck; b += 256) {
    bd[b] = Hs[(size_t)b * PB + blk];
    bs[b] = Hs[((size_t)nbuck + b) * PB + blk] - (int)E;
  }
  long long lo = (long long)blk * chunk;
  long long hi = lo + chunk; if (hi > E) hi = E;
  int is32 = detect_is32(ei, lo, hi, &s_flag);   // includes syncthreads
  for (long long e = lo + t; e < hi; e += 256) {
    int s = edge_at(ei, e, is32);
    int d = edge_at(ei, E + e, is32);
    int kb = d >> RSH;
    int rd = atomicAdd(&hd[kb], 1);
    pack_d[bd[kb] + rd] = ((unsigned)(d & (RNG - 1)) << 24) | (unsigned)s;
    int ks = s >> RSH;
    int rs = atomicAdd(&hs[ks], 1);
    src_loc[bs[ks] + rs] = (unsigned char)(s & (RNG - 1));
  }
}

// --- L2: per-bucket CSR build (row_ptr, nin, csr_src) + src-deg (nout) ---------
// --- + fused prescale: x1h[node,:] = bf16(in_feat[node,:] * nout[node]) --------
__global__ __launch_bounds__(256) void bucket_build_kernel(
    const unsigned* __restrict__ pack_d, const unsigned char* __restrict__ src_loc,
    const int* __restrict__ Hs, int nbuck, long long E, int n,
    int* __restrict__ row_ptr, float* __restrict__ nin, float* __restrict__ nout,
    int* __restrict__ csr_src,
    const float* __restrict__ in_feat, unsigned short* __restrict__ x1h) {
  __shared__ unsigned stage[CAP];
  __shared__ int cnt[RNG], cur[RNG], woff[4];
  __shared__ float fn[RNG];
  int b = blockIdx.x, t = threadIdx.x;
  int lane = t & 63, wv = t >> 6;
  int start = Hs[(size_t)b * PB];
  int end = Hs[(size_t)(b + 1) * PB];
  int len = end - start;
  cnt[t] = 0;
  __syncthreads();
  bool fits = (len <= CAP);
  for (int i = t; i < len; i += 256) {
    unsigned p = pack_d[start + i];
    if (fits) stage[i] = p;
    atomicAdd(&cnt[p >> 24], 1);
  }
  __syncthreads();
  int dreg = cnt[t];
  int isc = wave_incl_scan(dreg, lane);
  if (lane == 63) woff[wv] = isc;
  __syncthreads();
  int add = 0;
#pragma unroll
  for (int w = 0; w < 4; ++w) if (w < wv) add += woff[w];
  int excl = isc - dreg + add;
  int nd = b * RNG + t;
  if (nd < n) {
    row_ptr[nd] = start + excl;
    nin[nd] = rsqrtf((float)(dreg > 1 ? dreg : 1));
  }
  if (b == (int)gridDim.x - 1 && t == 0) row_ptr[n] = (int)E;
  cur[t] = excl;
  __syncthreads();
  for (int i = t; i < len; i += 256) {
    unsigned p = fits ? stage[i] : pack_d[start + i];
    int dl = (int)(p >> 24);
    int r = atomicAdd(&cur[dl], 1);
    csr_src[start + r] = (int)(p & 0xFFFFFFu);
  }
  // ---- src-degree phase -> nout (reuses cnt after dst phase completes) ----
  __syncthreads();
  cnt[t] = 0;
  __syncthreads();
  int sstart = Hs[(size_t)(nbuck + b) * PB] - (int)E;
  int send = Hs[(size_t)(nbuck + b + 1) * PB] - (int)E;
  for (int i = sstart + t; i < send; i += 256) atomicAdd(&cnt[src_loc[i]], 1);
  __syncthreads();
  float nv = rsqrtf((float)(cnt[t] > 1 ? cnt[t] : 1));
  fn[t] = nv;
  if (nd < n) nout[nd] = nv;
  __syncthreads();
  // ---- fused prescale for this bucket's nodes: 256 nodes x 128 f32 ----
  for (int c = t; c < RNG * DF / 8; c += 256) {
    int jl = c >> 4;                 // local node (chunk covers 8 of 128 cols)
    int node = b * RNG + jl;
    if (node >= n) break;            // trailing nodes only in last bucket
    float s = fn[jl];
    long long base = (long long)node * DF + (c & 15) * 8;
    float4 a = *((const float4*)(in_feat + base));
    float4 bb = *((const float4*)(in_feat + base + 4));
    uint4 o;
    o.x = pack2(a.x * s, a.y * s);
    o.y = pack2(a.z * s, a.w * s);
    o.z = pack2(bb.x * s, bb.y * s);
    o.w = pack2(bb.z * s, bb.w * s);
    *((uint4*)(x1h + base)) = o;
  }
}

// ---------------- aggregation: one wave per dst node, bf16 256B rows -----------
// (R10 half-wave form — proven 60.2us, service-rate floored: 177MB = 8 XCD x
// ~22MB compulsory L2 fills at ~3.4 TB/s random-line service.)
__global__ __launch_bounds__(256) void aggregate_bf16_kernel(
    const unsigned short* __restrict__ xh, const int* __restrict__ row_ptr,
    const int* __restrict__ csr_src, unsigned short* __restrict__ aggh, int n) {
  int wave = blockIdx.x * (blockDim.x >> 6) + (threadIdx.x >> 6);
  int lane = threadIdx.x & 63;
  if (wave >= n) return;
  int beg = row_ptr[wave], end = row_ptr[wave + 1];
  int deg = end - beg;
  int half = lane >> 5;       // which edge of the pair
  int sub = lane & 31;        // ushort4 slot within the 256B row
  float ax = 0.f, ay = 0.f, az = 0.f, aw = 0.f;
  for (int j0 = 0; j0 < deg; j0 += 64) {
    int li = beg + j0 + lane;
    int idx = csr_src[li < end ? li : (end - 1)];
    int cnt = deg - j0; if (cnt > 64) cnt = 64;
    int tfull = (cnt >> 4) << 3;   // pairs fully valid, in groups of 8
    for (int t0 = 0; t0 < tfull; t0 += 8) {
      ushort4 v[8];
#pragma unroll
      for (int u = 0; u < 8; ++u) {
        int s = __shfl(idx, 2 * (t0 + u) + half, 64);
        v[u] = *((const ushort4*)(xh + (size_t)s * DF) + sub);
      }
#pragma unroll
      for (int u = 0; u < 8; ++u) {
        ax += b2f(v[u].x); ay += b2f(v[u].y);
        az += b2f(v[u].z); aw += b2f(v[u].w);
      }
    }
    int cnt2 = (cnt + 1) >> 1;
    for (int t = tfull; t < cnt2; ++t) {
      int p = 2 * t + half;
      int s = __shfl(idx, p, 64);
      float m = (p < cnt) ? 1.f : 0.f;
      ushort4 v = *((const ushort4*)(xh + (size_t)s * DF) + sub);
      ax += b2f(v.x) * m; ay += b2f(v.y) * m;
      az += b2f(v.z) * m; aw += b2f(v.w) * m;
    }
  }
  ax += __shfl_down(ax, 32, 64);
  ay += __shfl_down(ay, 32, 64);
  az += __shfl_down(az, 32, 64);
  aw += __shfl_down(aw, 32, 64);
  if (half == 0) {
    uint2 pk; pk.x = pack2(ax, ay); pk.y = pack2(az, aw);
    *((uint2*)(aggh + (size_t)wave * DF + sub * 4)) = pk;
  }
}

// ------ MFMA transform: out[r,:] = (nin[r]*(aggh[r,:]@W) + b) * sc_out[r] ------
// One wave per 16-row stripe; W (hi+lo) in 64KiB LDS. Epilogue stages the
// 16x128 result through per-wave LDS (two 16x64 f32 halves) so global stores
// are 16B coalesced instead of scalar 2B/4B (MFMA C-layout is col-fragmented).
template <int BF16OUT>
__global__ __launch_bounds__(256) void transform_mfma_kernel(
    const unsigned short* __restrict__ aggh, const unsigned short* __restrict__ Wswz,
    const float* __restrict__ nin, const float* __restrict__ bias,
    const float* __restrict__ sc_out, void* __restrict__ outp, int n, int ntiles) {
  __shared__ uint4 Wl[4096];          // 64 KiB: [part(2)][tile(32)][lane(64)]
  __shared__ float ost[4][16 * 64];   // 16 KiB: per-wave 16x64 f32 stage
  int tid = threadIdx.x;
  for (int i = tid; i < 4096; i += 256) Wl[i] = ((const uint4*)Wswz)[i];
  __syncthreads();
  int l = tid & 63, wv = tid >> 6;
  int lr = l & 15, lg = l >> 4;
  float* st = ost[wv];
  for (int tile = blockIdx.x; tile < ntiles; tile += gridDim.x) {
    int rowbase = tile * 64 + wv * 16;
    int r_eff = rowbase + lr; if (r_eff > n - 1) r_eff = n - 1;
    const unsigned short* arow = aggh + (size_t)r_eff * DF + (lg << 3);
    bf16x8 a0 = *(const bf16x8*)(arow);
    bf16x8 a1 = *(const bf16x8*)(arow + 32);
    bf16x8 a2 = *(const bf16x8*)(arow + 64);
    bf16x8 a3 = *(const bf16x8*)(arow + 96);
    f32x4 acc[8];
#pragma unroll
    for (int jb = 0; jb < 8; ++jb) acc[jb] = (f32x4){0.f, 0.f, 0.f, 0.f};
#pragma unroll
    for (int ks = 0; ks < 4; ++ks) {
      bf16x8 a = (ks == 0) ? a0 : (ks == 1) ? a1 : (ks == 2) ? a2 : a3;
#pragma unroll
      for (int jb = 0; jb < 8; ++jb) {
        bf16x8 bh = *(const bf16x8*)&Wl[(jb * 4 + ks) * 64 + l];
        acc[jb] = __builtin_amdgcn_mfma_f32_16x16x32_bf16(a, bh, acc[jb], 0, 0, 0);
        bf16x8 bl = *(const bf16x8*)&Wl[2048 + (jb * 4 + ks) * 64 + l];
        acc[jb] = __builtin_amdgcn_mfma_f32_16x16x32_bf16(a, bl, acc[jb], 0, 0, 0);
      }
    }
    float ninq[4], soq[4];
#pragma unroll
    for (int q = 0; q < 4; ++q) {
      int r = rowbase + lg * 4 + q;
      ninq[q] = (r < n) ? nin[r] : 0.f;
      soq[q] = (r < n) ? (sc_out ? sc_out[r] : 1.f) : 0.f;
    }
    int rmax = n - rowbase;  // rows valid in this stripe (<=16 at the tail)
    // ---- epilogue: two 64-col halves through per-wave LDS (no barriers) ----
#pragma unroll
    for (int h = 0; h < 2; ++h) {
#pragma unroll
      for (int jb4 = 0; jb4 < 4; ++jb4) {
        int jb = h * 4 + jb4;
        float bj = bias[jb * 16 + lr];
#pragma unroll
        for (int q = 0; q < 4; ++q) {
          st[(lg * 4 + q) * 64 + jb4 * 16 + lr] = (acc[jb][q] * ninq[q] + bj) * soq[q];
        }
      }
      // read back coalesced (same wave; compiler inserts lgkmcnt waits)
      if (BF16OUT) {
#pragma unroll
        for (int it = 0; it < 2; ++it) {
          int id = it * 64 + l;          // 0..127: row(16) x 8-col-group(8)
          int row = id >> 3, c8 = id & 7;
          if (row < rmax) {
            float4 va = *((const float4*)&st[row * 64 + c8 * 8]);
            float4 vb = *((const float4*)&st[row * 64 + c8 * 8 + 4]);
            uint4 o;
            o.x = pack2(va.x, va.y); o.y = pack2(va.z, va.w);
            o.z = pack2(vb.x, vb.y); o.w = pack2(vb.z, vb.w);
            *((uint4*)((unsigned short*)outp + (size_t)(rowbase + row) * DF + h * 64 + c8 * 8)) = o;
          }
        }
      } else {
#pragma unroll
        for (int it = 0; it < 4; ++it) {
          int id = it * 64 + l;          // 0..255: row(16) x float4-group(16)
          int row = id >> 4, c4 = id & 15;
          if (row < rmax) {
            float4 v = *((const float4*)&st[row * 64 + c4 * 4]);
            *((float4*)((float*)outp + (size_t)(rowbase + row) * DF + h * 64 + c4 * 4)) = v;
          }
        }
      }
    }
  }
}

extern "C" void kernel_launch(void* const* d_in, const int* in_sizes, int n_in,
                              void* d_out, int out_size, void* d_ws, size_t ws_size,
                              hipStream_t stream) {
  const float* in_feat = (const float*)d_in[0];
  const void*  ei      = d_in[1];
  const float* W1 = (const float*)d_in[2];
  const float* b1 = (const float*)d_in[3];
  const float* W2 = (const float*)d_in[4];
  const float* b2 = (const float*)d_in[5];
  float* out = (float*)d_out;

  const int N = in_sizes[0] / DF;
  const long long E = in_sizes[1] / 2;
  const int nbuck = (N + RNG - 1) >> RSH;          // 391 for N=100K (must be <=512)
  const int M = 2 * nbuck * PB;                    // histogram array length
  const int NB2 = (M + 4095) / 4096;               // scan chunks
  const int chunk = (int)((E + PB - 1) / PB);      // edges per partition block
  const int ntiles = (N + 63) / 64;

  size_t off = 0;
  auto take = [&](size_t nb) -> char* {
    char* p = (char*)d_ws + off;
    off += (nb + 255) & ~(size_t)255;
    return p;
  };
  int* H          = (int*)take((size_t)M * 4);          // 1.6 MB
  int* Hs         = (int*)take((size_t)(M + 1) * 4);    // 1.6 MB
  int* partials   = (int*)take((size_t)NB2 * 4);
  int* row_ptr    = (int*)take((size_t)(N + 1) * 4);
  float* nout     = (float*)take((size_t)N * 4);
  float* nin      = (float*)take((size_t)N * 4);
  unsigned* pack_d = (unsigned*)take((size_t)E * 4);    // 6.4 MB
  unsigned char* src_loc = (unsigned char*)take((size_t)E); // 1.6 MB
  int* csr_src    = (int*)take((size_t)E * 4);          // 6.4 MB
  unsigned short* x1h = (unsigned short*)take((size_t)N * DF * 2); // 25.6 MB
  unsigned short* h1h = (unsigned short*)take((size_t)N * DF * 2); // 25.6 MB
  unsigned short* aggh = (unsigned short*)take((size_t)N * DF * 2); // 25.6 MB
  unsigned short* Wswz = (unsigned short*)take(2 * 65536);          // 128 KiB
  (void)ws_size; (void)n_in; (void)out_size;

  part_count_kernel<<<PB, 256, 0, stream>>>(ei, E, nbuck, chunk, H);
  chunk_sum_kernel<<<NB2 + 8, 1024, 0, stream>>>(H, partials, M, NB2, W1, W2, Wswz);
  scan_partials_kernel<<<1, 64, 0, stream>>>(partials, NB2);
  scan_chunk_kernel<<<NB2, 1024, 0, stream>>>(H, partials, Hs, M);
  part_scatter_kernel<<<PB, 256, 0, stream>>>(ei, E, nbuck, chunk, Hs, pack_d, src_loc);
  bucket_build_kernel<<<nbuck, 256, 0, stream>>>(pack_d, src_loc, Hs, nbuck, E, N,
                                                 row_ptr, nin, nout, csr_src,
                                                 in_feat, x1h);

  int ab = (N + 3) / 4;  // 4 waves (nodes) per 256-thread block
  // conv1: x1h -> aggh -> h1h = bf16((nin*(aggh@W1)+b1)*dout)
  aggregate_bf16_kernel<<<ab, 256, 0, stream>>>(x1h, row_ptr, csr_src, aggh, N);
  transform_mfma_kernel<1><<<512, 256, 0, stream>>>(aggh, Wswz, nin, b1, nout, h1h, N, ntiles);
  // conv2: h1h -> aggh -> out (f32)
  aggregate_bf16_kernel<<<ab, 256, 0, stream>>>(h1h, row_ptr, csr_src, aggh, N);
  transform_mfma_kernel<0><<<512, 256, 0, stream>>>(aggh, Wswz + 32768, nin, b2, nullptr, out, N, ntiles);
}